// Round 4
// baseline (1303.428 us; speedup 1.0000x reference)
//
#include <hip/hip_runtime.h>

typedef _Float16 v8h __attribute__((ext_vector_type(8)));
typedef float    v4f __attribute__((ext_vector_type(4)));

__device__ __forceinline__ float fast_tanh(float x) {
    float e = __expf(2.0f * x);
    return 1.0f - 2.0f / (e + 1.0f);
}

// ---------------------------------------------------------------------------
// pack layout (halves), nt-major so consumption is sequential 4KB chunks:
//  hidden: idx = ((((pipe*3+l)*8 + nt)*4 + kk)*64 + lane)*8 + j     [0, 98304)
//          value = Wh[l][k = kk*32 + (lane>>4)*8 + j][n = nt*16 + (lane&15)]
//  L0:     98304 + ((pipe*8 + nt)*64 + lane)*8 + j                  [98304, 106496)
//          value = Win[k = (lane>>4)*8+j][n] for k < in_dim else 0
// ---------------------------------------------------------------------------
__global__ void pack_weights(const float* __restrict__ dpWh,
                             const float* __restrict__ icWh,
                             const float* __restrict__ dpWin,
                             const float* __restrict__ icWin,
                             _Float16* __restrict__ out) {
    int idx = blockIdx.x * 256 + threadIdx.x;
    if (idx < 98304) {
        int j    = idx & 7;
        int lane = (idx >> 3) & 63;
        int kk   = (idx >> 9) & 3;
        int nt   = (idx >> 11) & 7;
        int lp   = idx >> 14;           // 0..5
        int l    = lp % 3;
        const float* src = (lp >= 3) ? icWh : dpWh;
        int k = kk * 32 + (lane >> 4) * 8 + j;
        int n = nt * 16 + (lane & 15);
        out[idx] = (_Float16)src[(l * 128 + k) * 128 + n];
    } else if (idx < 106496) {
        int f    = idx - 98304;
        int j    = f & 7;
        int lane = (f >> 3) & 63;
        int nt   = (f >> 9) & 7;
        int pipe = (f >> 12) & 1;
        int k = (lane >> 4) * 8 + j;
        int n = nt * 16 + (lane & 15);
        float v = 0.0f;
        if (pipe == 0) { if (k < 4) v = dpWin[k * 128 + n]; }
        else           { if (k < 3) v = icWin[k * 128 + n]; }
        out[idx] = (_Float16)v;
    }
}

// LDS (dynamic, 39808 B -> 4 blocks/CU):
//   [0,     34816)  act  : 4 waves x 32 rows x 136 halves (8-half row pad)
//   [34816, 36864)  btabh: f16[2][4][128]  ({Bin, Bh0..2} per pipe)
//   [36864, 37888)  woutb: f32[2][128]
//   [37888, 38912)  cbuf : f32[2][4][32]   (ping-pong by batch parity)
//   [38912, 39808)  rowb : f32[2][8][14]   (per-row geometry, ping-pong)
#define SMEM_BYTES 39808
#define ROWH 136   // halves per act row

__launch_bounds__(256, 4)
__global__ void node_main(const float* __restrict__ tx,
                          const float* __restrict__ dpBin, const float* __restrict__ dpBh,
                          const float* __restrict__ dpWout, const float* __restrict__ dpBout,
                          const float* __restrict__ icBin, const float* __restrict__ icBh,
                          const float* __restrict__ icWout, const float* __restrict__ icBout,
                          const _Float16* __restrict__ pack,
                          float* __restrict__ outPot, float* __restrict__ outAcc,
                          int N)
{
    extern __shared__ char smem[];
    _Float16* act   = (_Float16*)smem;
    _Float16* btabh = (_Float16*)(smem + 34816);
    float* woutb = (float*)(smem + 36864);
    float* cbuf  = (float*)(smem + 37888);
    float* rowb  = (float*)(smem + 38912);

    const int tid  = threadIdx.x;
    const int wave = tid >> 6;
    const int lane = tid & 63;
    const int l15  = lane & 15;
    const int s    = lane >> 4;

    if (tid < 128) {
        btabh[tid]       = (_Float16)dpBin[tid];
        btabh[512 + tid] = (_Float16)icBin[tid];
        woutb[tid]       = dpWout[tid];
        woutb[128 + tid] = icWout[tid];
    }
    for (int i = tid; i < 384; i += 256) {
        btabh[128 + i] = (_Float16)dpBh[i];
        btabh[640 + i] = (_Float16)icBh[i];
    }
    __syncthreads();

    const bool isic = (wave == 3);
    const float node1 = (wave == 0) ? (1.0f - 0.7745966692414834f)
                      : (wave == 1) ? 1.0f
                      : (wave == 2) ? (1.0f + 0.7745966692414834f) : 0.0f;  // node+1
    const _Float16* hbase  = pack + (isic ? 49152 : 0);          // pipe*3*16384
    const _Float16* l0base = pack + 98304 + (isic ? 4096 : 0);
    const _Float16* btabp = btabh + (isic ? 512 : 0);
    const float* wop   = woutb + (isic ? 128 : 0);
    const float  boutv = isic ? icBout[0] : dpBout[0];
    _Float16* actw = act + wave * (32 * ROWH);

    // static per-lane bases (all further addressing is compile-time immediates)
    _Float16*       ep_base  = actw + s * (4 * ROWH) + l15;   // + mt*16*ROWH + nt*16, rows +q*ROWH
    const _Float16* afr_base = actw + l15 * ROWH + s * 8;     // + mt*16*ROWH + kk*32
    const _Float16* ph4_base = actw + (lane & 31) * ROWH + (lane >> 5) * 64;  // + c*8

    auto epilogue = [&](v4f* acc, int nt) {
        #pragma unroll
        for (int mt = 0; mt < 2; mt++) {
            v4f v = acc[mt];
            float h = fast_tanh(v[0]);
            float D = 1.0f - h * h;
            _Float16* p = ep_base + mt * (16 * ROWH) + nt * 16;
            p[0 * ROWH] = (_Float16)h;
            p[1 * ROWH] = (_Float16)(D * v[1]);
            p[2 * ROWH] = (_Float16)(D * v[2]);
            p[3 * ROWH] = (_Float16)(D * v[3]);
        }
    };

    // persistent B ring: 4 slots x 4 kk, lookahead 4, consume-then-refill
    v8h ring[4][4];
    {
        const _Float16* rl = hbase + (lane << 3);
        #pragma unroll
        for (int sl = 0; sl < 4; sl++)
            #pragma unroll
            for (int kk = 0; kk < 4; kk++)
                ring[sl][kk] = *(const v8h*)(rl + ((sl * 4 + kk) << 9));
    }

    auto run_hidden = [&](const _Float16* cur, const _Float16* nxt, const _Float16* bias) {
        const _Float16* cl = cur + (lane << 3);
        const _Float16* nl = nxt + (lane << 3);
        v8h afr[2][4];
        #pragma unroll
        for (int mt = 0; mt < 2; mt++)
            #pragma unroll
            for (int kk = 0; kk < 4; kk++)
                afr[mt][kk] = *(const v8h*)(afr_base + mt * (16 * ROWH) + kk * 32);
        #pragma unroll
        for (int nt = 0; nt < 8; nt++) {
            int slot = nt & 3;
            float bv = (float)bias[nt * 16 + l15];
            v4f acc[2];
            #pragma unroll
            for (int mt = 0; mt < 2; mt++) { v4f z = {bv, 0.0f, 0.0f, 0.0f}; acc[mt] = z; }
            #pragma unroll
            for (int kk = 0; kk < 4; kk++)
                #pragma unroll
                for (int mt = 0; mt < 2; mt++)
                    acc[mt] = __builtin_amdgcn_mfma_f32_16x16x32_f16(afr[mt][kk], ring[slot][kk], acc[mt], 0, 0, 0);
            #pragma unroll
            for (int kk = 0; kk < 4; kk++) {
                if (nt < 4) ring[slot][kk] = *(const v8h*)(cl + (((nt + 4) * 4 + kk) << 9));
                else        ring[slot][kk] = *(const v8h*)(nl + (((nt - 4) * 4 + kk) << 9));
            }
            epilogue(acc, nt);
        }
    };

    const int nbat = (N + 7) >> 3;
    int par = 0;
    for (int b = blockIdx.x; b < nbat; b += gridDim.x, par ^= 1) {
        // ---- L0 weight prefetch ----
        v8h bfr0[8];
        {
            const _Float16* l0l = l0base + (lane << 3);
            #pragma unroll
            for (int nt = 0; nt < 8; nt++)
                bfr0[nt] = *(const v8h*)(l0l + (nt << 9));
        }

        // ---- per-lane geometry for phys row (l15&7), transient ----
        float ttf, rrf, thf, phf;
        {
            int prow = b * 8 + (l15 & 7);
            float4 q = (prow < N) ? ((const float4*)tx)[prow] : make_float4(0.f, 1.f, 1.f, 1.f);
            float t = q.x, x = q.y, y = q.z, z = q.w;
            float r2 = x * x + y * y + z * z;
            float r  = sqrtf(r2 + 1e-12f);
            float rinv = 1.0f / r;
            float uc = fminf(1.0f, fmaxf(-1.0f, z * rinv));
            float th = acosf(uc);
            float ph = atan2f(y, x);
            ttf = t; rrf = r; thf = th; phf = ph;
            if (wave == 0 && lane < 8) {
                float rinv3 = rinv * rinv * rinv;
                float dacos = -1.0f / sqrtf(fmaxf(1.0f - uc * uc, 1e-30f));
                float rho2 = fmaxf(x * x + y * y, 1e-30f);
                float opr  = 1.0f + r;
                float den  = r * r + 0.1f;
                float isq  = 1.0f / sqrtf(den);
                float* rb = rowb + par * 112 + lane * 14;
                rb[0]  = t;
                rb[1]  = x * rinv; rb[2] = y * rinv; rb[3] = z * rinv;
                rb[4]  = dacos * (-x * z * rinv3);
                rb[5]  = dacos * (-y * z * rinv3);
                rb[6]  = dacos * (rinv - z * z * rinv3);
                rb[7]  = -y / rho2;
                rb[8]  =  x / rho2;
                rb[9]  = -1.0f / opr;          // sEnv
                rb[10] =  1.0f / (opr * opr);  // dsdr
                rb[11] = -isq;                 // Aan
                rb[12] = r * isq * isq * isq;  // dAdr
            }
        }

        // distribute (t,r,th,ph) of phys row p = mt*4 + (l15>>2)
        float ttv[2], rrv[2], thv[2], phv[2];
        #pragma unroll
        for (int mt = 0; mt < 2; mt++) {
            int src = (lane & 48) + mt * 4 + ((lane >> 2) & 3);
            ttv[mt] = __shfl(ttf, src);
            rrv[mt] = __shfl(rrf, src);
            thv[mt] = __shfl(thf, src);
            phv[mt] = __shfl(phf, src);
        }

        // ---- layer 0: K=32 MFMA (primal inputs + unit tangent seeds in A) ----
        {
            int stream = l15 & 3;
            v8h a0[2];
            #pragma unroll
            for (int mt = 0; mt < 2; mt++) {
                bool p = (stream == 0);
                float e0, e1, e2, e3;
                if (isic) {
                    e0 = p ? rrv[mt] : (stream == 1 ? 1.0f : 0.0f);
                    e1 = p ? thv[mt] : (stream == 2 ? 1.0f : 0.0f);
                    e2 = p ? phv[mt] : (stream == 3 ? 1.0f : 0.0f);
                    e3 = 0.0f;
                } else {
                    float ts = 0.5f * ttv[mt] * node1;
                    e0 = p ? ts : 0.0f;
                    e1 = p ? rrv[mt] : (stream == 1 ? 1.0f : 0.0f);
                    e2 = p ? thv[mt] : (stream == 2 ? 1.0f : 0.0f);
                    e3 = p ? phv[mt] : (stream == 3 ? 1.0f : 0.0f);
                }
                v8h a = {};
                a[0] = (_Float16)e0; a[1] = (_Float16)e1;
                a[2] = (_Float16)e2; a[3] = (_Float16)e3;
                v8h az = {};
                a0[mt] = (s == 0) ? a : az;
            }
            #pragma unroll
            for (int nt = 0; nt < 8; nt++) {
                float bv = (float)btabp[nt * 16 + l15];
                v4f acc[2];
                #pragma unroll
                for (int mt = 0; mt < 2; mt++) { v4f zz = {bv, 0.0f, 0.0f, 0.0f}; acc[mt] = zz; }
                #pragma unroll
                for (int mt = 0; mt < 2; mt++)
                    acc[mt] = __builtin_amdgcn_mfma_f32_16x16x32_f16(a0[mt], bfr0[nt], acc[mt], 0, 0, 0);
                epilogue(acc, nt);
            }
        }

        // ---- hidden layers (K=128); ring streams h1->h2->h3->(next batch h1) ----
        run_hidden(hbase,          hbase + 16384, btabp + 128);
        run_hidden(hbase + 16384,  hbase + 32768, btabp + 256);
        run_hidden(hbase + 32768,  hbase,         btabp + 384);

        // ---- output dot (fp32), split across lane halves ----
        {
            float sum = 0.0f;
            #pragma unroll
            for (int c = 0; c < 8; c++) {
                v8h hv = *(const v8h*)(ph4_base + c * 8);
                #pragma unroll
                for (int j = 0; j < 8; j++)
                    sum += (float)hv[j] * wop[(lane >> 5) * 64 + c * 8 + j];
            }
            sum += __shfl_xor(sum, 32);
            if (lane < 32) {
                if ((lane & 3) == 0) sum += boutv;
                cbuf[par * 128 + wave * 32 + lane] = sum;
            }
        }
        __syncthreads();

        // ---- quadrature + envelope + chain rule (wave 0, lanes 0-7) ----
        if (wave == 0 && lane < 8) {
            int row = b * 8 + lane;
            if (row < N) {
                const float* cb = cbuf + par * 128;
                const float* rb = rowb + par * 112 + lane * 14;
                float t = rb[0];
                float ah = 0.5f * t;
                float vic = cb[96 + (lane << 2) + 0];
                float g0  = cb[96 + (lane << 2) + 1];
                float g1  = cb[96 + (lane << 2) + 2];
                float g2  = cb[96 + (lane << 2) + 3];
                float dsum = 0.f, ds0 = 0.f, ds1 = 0.f, ds2 = 0.f;
                const float wq[3] = {0.5555555555555556f, 0.8888888888888889f, 0.5555555555555556f};
                #pragma unroll
                for (int qq = 0; qq < 3; qq++) {
                    float w = wq[qq];
                    dsum += w * cb[qq * 32 + (lane << 2) + 0];
                    ds0  += w * cb[qq * 32 + (lane << 2) + 1];
                    ds1  += w * cb[qq * 32 + (lane << 2) + 2];
                    ds2  += w * cb[qq * 32 + (lane << 2) + 3];
                }
                float tcv  = vic + ah * dsum;
                float dtc0 = g0 + ah * ds0, dtc1 = g1 + ah * ds1, dtc2 = g2 + ah * ds2;
                float sEnv = rb[9], dsdr = rb[10], Aan = rb[11], dAdr = rb[12];
                float pot = tcv * sEnv + Aan;
                float gx0 = sEnv * dtc0 + tcv * dsdr + dAdr;
                float gx1 = sEnv * dtc1;
                float gx2 = sEnv * dtc2;
                float ax = -(gx0 * rb[1] + gx1 * rb[4] + gx2 * rb[7]);
                float ay = -(gx0 * rb[2] + gx1 * rb[5] + gx2 * rb[8]);
                float az = -(gx0 * rb[3] + gx1 * rb[6]);
                outPot[row] = pot;
                outAcc[row * 3 + 0] = ax;
                outAcc[row * 3 + 1] = ay;
                outAcc[row * 3 + 2] = az;
            }
        }
    }
}

extern "C" void kernel_launch(void* const* d_in, const int* in_sizes, int n_in,
                              void* d_out, int out_size, void* d_ws, size_t ws_size,
                              hipStream_t stream) {
    (void)n_in; (void)out_size;
    const float* tx     = (const float*)d_in[0];
    const float* dpWin  = (const float*)d_in[1];
    const float* dpBin  = (const float*)d_in[2];
    const float* dpWh   = (const float*)d_in[3];
    const float* dpBh   = (const float*)d_in[4];
    const float* dpWout = (const float*)d_in[5];
    const float* dpBout = (const float*)d_in[6];
    const float* icWin  = (const float*)d_in[7];
    const float* icBin  = (const float*)d_in[8];
    const float* icWh   = (const float*)d_in[9];
    const float* icBh   = (const float*)d_in[10];
    const float* icWout = (const float*)d_in[11];
    const float* icBout = (const float*)d_in[12];

    int N = in_sizes[0] / 4;
    if (ws_size < (size_t)(106496 * sizeof(_Float16))) return;
    _Float16* pack = (_Float16*)d_ws;
    float* outPot = (float*)d_out;
    float* outAcc = outPot + N;

    pack_weights<<<(106496 + 255) / 256, 256, 0, stream>>>(dpWh, icWh, dpWin, icWin, pack);

    (void)hipFuncSetAttribute(reinterpret_cast<const void*>(node_main),
                              hipFuncAttributeMaxDynamicSharedMemorySize, SMEM_BYTES);
    node_main<<<1024, 256, SMEM_BYTES, stream>>>(tx,
        dpBin, dpBh, dpWout, dpBout,
        icBin, icBh, icWout, icBout,
        pack, outPot, outAcc, N);
}

// Round 5
// 419.979 us; speedup vs baseline: 3.1036x; 3.1036x over previous
//
#include <hip/hip_runtime.h>

typedef _Float16 v8h __attribute__((ext_vector_type(8)));
typedef float    v4f __attribute__((ext_vector_type(4)));

template<int V> struct IC { static constexpr int value = V; };

__device__ __forceinline__ float fast_tanh(float x) {
    float e = __expf(2.0f * x);
    return 1.0f - 2.0f / (e + 1.0f);
}

// ---------------------------------------------------------------------------
// pack layout (halves), same as validated rounds 2-4:
//  hidden: idx = ((((pipe*3+l)*8 + nt)*4 + kk)*64 + lane)*8 + j     [0, 98304)
//          value = Wh[l][k = kk*32 + (lane>>4)*8 + j][n = nt*16 + (lane&15)]
//  L0:     98304 + ((pipe*8 + nt)*64 + lane)*8 + j                  [98304, 106496)
//          value = Win[k = (lane>>4)*8+j][n] for k < in_dim else 0
// ---------------------------------------------------------------------------
__global__ void pack_weights(const float* __restrict__ dpWh,
                             const float* __restrict__ icWh,
                             const float* __restrict__ dpWin,
                             const float* __restrict__ icWin,
                             _Float16* __restrict__ out) {
    int idx = blockIdx.x * 256 + threadIdx.x;
    if (idx < 98304) {
        int j    = idx & 7;
        int lane = (idx >> 3) & 63;
        int kk   = (idx >> 9) & 3;
        int nt   = (idx >> 11) & 7;
        int lp   = idx >> 14;           // 0..5
        int l    = lp % 3;
        const float* src = (lp >= 3) ? icWh : dpWh;
        int k = kk * 32 + (lane >> 4) * 8 + j;
        int n = nt * 16 + (lane & 15);
        out[idx] = (_Float16)src[(l * 128 + k) * 128 + n];
    } else if (idx < 106496) {
        int f    = idx - 98304;
        int j    = f & 7;
        int lane = (f >> 3) & 63;
        int nt   = (f >> 9) & 7;
        int pipe = (f >> 12) & 1;
        int k = (lane >> 4) * 8 + j;
        int n = nt * 16 + (lane & 15);
        float v = 0.0f;
        if (pipe == 0) { if (k < 4) v = dpWin[k * 128 + n]; }
        else           { if (k < 3) v = icWin[k * 128 + n]; }
        out[idx] = (_Float16)v;
    }
}

// LDS (dynamic, 140288 B -> 1 block/CU, 8 waves = 2/SIMD):
//   [0,      69632)  act0 : 256 rows x 136 halves (row = set*64 + phys*4 + stream)
//   [69632, 139264)  act1 : ping-pong partner
//   [139264,140288)  cbuf : f32[256] per-virtual-row scalar outputs
#define ROWH 136
#define ABUFH (256 * ROWH)
#define SMEM_BYTES (2 * ABUFH * 2 + 1024)

__launch_bounds__(512, 2)
__global__ void node_main(const float* __restrict__ tx,
                          const float* __restrict__ dpBin, const float* __restrict__ dpBh,
                          const float* __restrict__ dpWout, const float* __restrict__ dpBout,
                          const float* __restrict__ icBin, const float* __restrict__ icBh,
                          const float* __restrict__ icWout, const float* __restrict__ icBout,
                          const _Float16* __restrict__ pack,
                          float* __restrict__ outPot, float* __restrict__ outAcc,
                          int N)
{
    extern __shared__ char smem[];
    _Float16* act0 = (_Float16*)smem;
    _Float16* act1 = act0 + ABUFH;
    float* cbuf = (float*)(smem + 2 * ABUFH * 2);

    const int tid  = threadIdx.x;
    const int wave = tid >> 6;          // 0..7 = my 16-column slice nt
    const int lane = tid & 63;
    const int l15  = lane & 15;
    const int s    = lane >> 4;
    const int col  = wave * 16 + l15;

    // ---- persistent weights: my nt-slice of all 6 hidden layers (96 VGPR) ----
    v8h wreg[6][4];
    #pragma unroll
    for (int L = 0; L < 6; L++)
        #pragma unroll
        for (int kk = 0; kk < 4; kk++)
            wreg[L][kk] = *(const v8h*)(pack + (((L * 8 + wave) * 4 + kk) << 9) + (lane << 3));
    v8h wl0[2];
    wl0[0] = *(const v8h*)(pack + 98304 + ((wave * 64 + lane) << 3));
    wl0[1] = *(const v8h*)(pack + 98304 + (((8 + wave) * 64 + lane) << 3));

    float biasv[8];   // [0]=dp Bin, [1..3]=dp Bh, [4]=ic Bin, [5..7]=ic Bh (my col)
    biasv[0] = dpBin[col];
    biasv[4] = icBin[col];
    #pragma unroll
    for (int l = 0; l < 3; l++) {
        biasv[1 + l] = dpBh[l * 128 + col];
        biasv[5 + l] = icBh[l * 128 + col];
    }

    // wout fragment for output dot: my rows are pipe (wave>=6 ? ic : dp)
    v8h wouth[4];
    {
        const float* wsrc = (wave >= 6) ? icWout : dpWout;
        #pragma unroll
        for (int c = 0; c < 4; c++) {
            v8h w;
            #pragma unroll
            for (int j = 0; j < 8; j++)
                w[j] = (_Float16)wsrc[(lane & 3) * 32 + c * 8 + j];
            wouth[c] = w;
        }
    }
    const float boutv = (wave >= 6) ? icBout[0] : dpBout[0];

    // ---- static LDS bases (rest of addressing = compile-time immediates) ----
    const int ep_off = s * (4 * ROWH) + col;        // epilogue write base
    const int rd_off = l15 * ROWH + s * 8;          // A-fragment read base
    _Float16* ep0a = act0 + ep_off;  _Float16* ep0b = ep0a + 128 * ROWH;
    _Float16* ep1a = act1 + ep_off;  _Float16* ep1b = ep1a + 128 * ROWH;
    const _Float16* rd0a = act0 + rd_off;  const _Float16* rd0b = rd0a + 128 * ROWH;
    const _Float16* rd1a = act1 + rd_off;  const _Float16* rd1b = rd1a + 128 * ROWH;

    auto epi = [&](v4f v, _Float16* wlo, _Float16* whi, int m) {
        float h = fast_tanh(v[0]);
        float D = 1.0f - h * h;
        _Float16* base = (m & 8) ? whi : wlo;
        int o = (m & 7) * (16 * ROWH);
        base[o           ] = (_Float16)h;
        base[o + 1 * ROWH] = (_Float16)(D * v[1]);
        base[o + 2 * ROWH] = (_Float16)(D * v[2]);
        base[o + 3 * ROWH] = (_Float16)(D * v[3]);
    };

    // one hidden layer: 16 M-tiles (12 dp + 4 ic), weights stationary in VGPRs
    auto hpass = [&](auto Lc, const _Float16* rlo, const _Float16* rhi,
                     _Float16* wlo, _Float16* whi) {
        constexpr int ldp = decltype(Lc)::value;   // dp layer index 0..2
        constexpr int lic = ldp + 3;
        const float bdp = biasv[1 + ldp];
        const float bic = biasv[5 + ldp];
        #pragma unroll
        for (int m = 0; m < 16; m++) {
            const _Float16* rb = (m & 8) ? rhi : rlo;
            int ro = (m & 7) * (16 * ROWH);
            v8h a0 = *(const v8h*)(rb + ro);
            v8h a1 = *(const v8h*)(rb + ro + 32);
            v8h a2 = *(const v8h*)(rb + ro + 64);
            v8h a3 = *(const v8h*)(rb + ro + 96);
            float bv = (m < 12) ? bdp : bic;
            v4f acc = {bv, 0.0f, 0.0f, 0.0f};
            if (m < 12) {
                acc = __builtin_amdgcn_mfma_f32_16x16x32_f16(a0, wreg[ldp][0], acc, 0, 0, 0);
                acc = __builtin_amdgcn_mfma_f32_16x16x32_f16(a1, wreg[ldp][1], acc, 0, 0, 0);
                acc = __builtin_amdgcn_mfma_f32_16x16x32_f16(a2, wreg[ldp][2], acc, 0, 0, 0);
                acc = __builtin_amdgcn_mfma_f32_16x16x32_f16(a3, wreg[ldp][3], acc, 0, 0, 0);
            } else {
                acc = __builtin_amdgcn_mfma_f32_16x16x32_f16(a0, wreg[lic][0], acc, 0, 0, 0);
                acc = __builtin_amdgcn_mfma_f32_16x16x32_f16(a1, wreg[lic][1], acc, 0, 0, 0);
                acc = __builtin_amdgcn_mfma_f32_16x16x32_f16(a2, wreg[lic][2], acc, 0, 0, 0);
                acc = __builtin_amdgcn_mfma_f32_16x16x32_f16(a3, wreg[lic][3], acc, 0, 0, 0);
            }
            epi(acc, wlo, whi, m);
        }
    };

    const float NP0 = 1.0f - 0.7745966692414834f;   // GL node+1
    const float NP2 = 1.0f + 0.7745966692414834f;

    const int nbat = (N + 15) >> 4;
    for (int b = blockIdx.x; b < nbat; b += gridDim.x) {
        // ---- geometry (every wave, lanes mirror phys rows 0..15) ----
        int prow = b * 16 + (lane & 15);
        float4 q = (prow < N) ? ((const float4*)tx)[prow] : make_float4(0.f, 1.f, 1.f, 1.f);
        float t = q.x, x = q.y, y = q.z, z = q.w;
        float r2 = x * x + y * y + z * z;
        float r  = sqrtf(r2 + 1e-12f);
        float rinv = 1.0f / r;
        float uc = fminf(1.0f, fmaxf(-1.0f, z * rinv));
        float th = acosf(uc);
        float ph = atan2f(y, x);
        // derivative terms (used only by wave 0 at combine; cheap, keep uniform)
        float rinv3 = rinv * rinv * rinv;
        float dacos = -1.0f / sqrtf(fmaxf(1.0f - uc * uc, 1e-30f));
        float dthx = dacos * (-x * z * rinv3);
        float dthy = dacos * (-y * z * rinv3);
        float dthz = dacos * (rinv - z * z * rinv3);
        float rho2 = fmaxf(x * x + y * y, 1e-30f);
        float dphx = -y / rho2;
        float dphy =  x / rho2;
        float opr  = 1.0f + r;
        float sEnv = -1.0f / opr;
        float dsdr =  1.0f / (opr * opr);
        float den  = r * r + 0.1f;
        float isq  = 1.0f / sqrtf(den);
        float Aan  = -isq;
        float dAdr = r * isq * isq * isq;
        float xr = x * rinv, yr = y * rinv, zr = z * rinv;

        // distribute (t,r,th,ph) of phys p = mt*4 + (l15>>2) to this lane
        float tv[4], rv[4], thv[4], phv[4];
        #pragma unroll
        for (int mt = 0; mt < 4; mt++) {
            int src = mt * 4 + ((lane >> 2) & 3);
            tv[mt]  = __shfl(t,  src);
            rv[mt]  = __shfl(r,  src);
            thv[mt] = __shfl(th, src);
            phv[mt] = __shfl(ph, src);
        }

        // ---- L0: 16 M-tiles, K=32 MFMA, seeds built in-register -> act0 ----
        {
            int st = l15 & 3;
            bool p = (st == 0);
            #pragma unroll
            for (int m = 0; m < 16; m++) {
                int set = m >> 2, mt = m & 3;
                float e0, e1, e2, e3;
                if (set < 3) {
                    float np1 = (set == 0) ? NP0 : (set == 1) ? 1.0f : NP2;
                    float ts = 0.5f * tv[mt] * np1;
                    e0 = p ? ts : 0.0f;
                    e1 = p ? rv[mt]  : (st == 1 ? 1.0f : 0.0f);
                    e2 = p ? thv[mt] : (st == 2 ? 1.0f : 0.0f);
                    e3 = p ? phv[mt] : (st == 3 ? 1.0f : 0.0f);
                } else {
                    e0 = p ? rv[mt]  : (st == 1 ? 1.0f : 0.0f);
                    e1 = p ? thv[mt] : (st == 2 ? 1.0f : 0.0f);
                    e2 = p ? phv[mt] : (st == 3 ? 1.0f : 0.0f);
                    e3 = 0.0f;
                }
                v8h a = {};
                a[0] = (_Float16)e0; a[1] = (_Float16)e1;
                a[2] = (_Float16)e2; a[3] = (_Float16)e3;
                v8h az = {};
                v8h am = (s == 0) ? a : az;
                float bv = (set < 3) ? biasv[0] : biasv[4];
                v4f acc = {bv, 0.0f, 0.0f, 0.0f};
                acc = __builtin_amdgcn_mfma_f32_16x16x32_f16(am, wl0[set < 3 ? 0 : 1], acc, 0, 0, 0);
                epi(acc, ep0a, ep0b, m);
            }
        }
        __syncthreads();                                   // bar1: act0 ready

        hpass(IC<0>{}, rd0a, rd0b, ep1a, ep1b);            // h1: act0 -> act1
        __syncthreads();                                   // bar2
        hpass(IC<1>{}, rd1a, rd1b, ep0a, ep0b);            // h2: act1 -> act0
        __syncthreads();                                   // bar3
        hpass(IC<2>{}, rd0a, rd0b, ep1a, ep1b);            // h3: act0 -> act1
        __syncthreads();                                   // bar4: act1 final

        // ---- output dot: my 32 rows, 4 lanes per row ----
        #pragma unroll
        for (int pp = 0; pp < 2; pp++) {
            int row = wave * 32 + pp * 16 + (lane >> 2);
            const _Float16* rp = act1 + row * ROWH + (lane & 3) * 32;
            float sum = 0.0f;
            #pragma unroll
            for (int c = 0; c < 4; c++) {
                v8h hv = *(const v8h*)(rp + c * 8);
                #pragma unroll
                for (int j = 0; j < 8; j++)
                    sum += (float)hv[j] * (float)wouth[c][j];
            }
            sum += __shfl_xor(sum, 1);
            sum += __shfl_xor(sum, 2);
            if ((lane & 3) == 0) {
                if (((lane >> 2) & 3) == 0) sum += boutv;  // bias on primal stream
                cbuf[row] = sum;
            }
        }
        __syncthreads();                                   // bar5: cbuf ready

        // ---- quadrature + envelope + chain rule (wave 0, lanes 0-15) ----
        if (wave == 0 && lane < 16) {
            int row = b * 16 + lane;
            if (row < N) {
                float ah = 0.5f * t;
                float vic = cbuf[192 + lane * 4 + 0];
                float g0  = cbuf[192 + lane * 4 + 1];
                float g1  = cbuf[192 + lane * 4 + 2];
                float g2  = cbuf[192 + lane * 4 + 3];
                float dsum = 0.f, ds0 = 0.f, ds1 = 0.f, ds2 = 0.f;
                const float wq[3] = {0.5555555555555556f, 0.8888888888888889f, 0.5555555555555556f};
                #pragma unroll
                for (int qq = 0; qq < 3; qq++) {
                    float w = wq[qq];
                    dsum += w * cbuf[qq * 64 + lane * 4 + 0];
                    ds0  += w * cbuf[qq * 64 + lane * 4 + 1];
                    ds1  += w * cbuf[qq * 64 + lane * 4 + 2];
                    ds2  += w * cbuf[qq * 64 + lane * 4 + 3];
                }
                float tcv  = vic + ah * dsum;
                float dtc0 = g0 + ah * ds0, dtc1 = g1 + ah * ds1, dtc2 = g2 + ah * ds2;
                float pot = tcv * sEnv + Aan;
                float gx0 = sEnv * dtc0 + tcv * dsdr + dAdr;
                float gx1 = sEnv * dtc1;
                float gx2 = sEnv * dtc2;
                float ax = -(gx0 * xr + gx1 * dthx + gx2 * dphx);
                float ay = -(gx0 * yr + gx1 * dthy + gx2 * dphy);
                float az = -(gx0 * zr + gx1 * dthz);
                outPot[row] = pot;
                outAcc[row * 3 + 0] = ax;
                outAcc[row * 3 + 1] = ay;
                outAcc[row * 3 + 2] = az;
            }
        }
    }
}

extern "C" void kernel_launch(void* const* d_in, const int* in_sizes, int n_in,
                              void* d_out, int out_size, void* d_ws, size_t ws_size,
                              hipStream_t stream) {
    (void)n_in; (void)out_size;
    const float* tx     = (const float*)d_in[0];
    const float* dpWin  = (const float*)d_in[1];
    const float* dpBin  = (const float*)d_in[2];
    const float* dpWh   = (const float*)d_in[3];
    const float* dpBh   = (const float*)d_in[4];
    const float* dpWout = (const float*)d_in[5];
    const float* dpBout = (const float*)d_in[6];
    const float* icWin  = (const float*)d_in[7];
    const float* icBin  = (const float*)d_in[8];
    const float* icWh   = (const float*)d_in[9];
    const float* icBh   = (const float*)d_in[10];
    const float* icWout = (const float*)d_in[11];
    const float* icBout = (const float*)d_in[12];

    int N = in_sizes[0] / 4;
    if (ws_size < (size_t)(106496 * sizeof(_Float16))) return;
    _Float16* pack = (_Float16*)d_ws;
    float* outPot = (float*)d_out;
    float* outAcc = outPot + N;

    pack_weights<<<(106496 + 255) / 256, 256, 0, stream>>>(dpWh, icWh, dpWin, icWin, pack);

    (void)hipFuncSetAttribute(reinterpret_cast<const void*>(node_main),
                              hipFuncAttributeMaxDynamicSharedMemorySize, SMEM_BYTES);
    node_main<<<256, 512, SMEM_BYTES, stream>>>(tx,
        dpBin, dpBh, dpWout, dpBout,
        icBin, icBh, icWout, icBout,
        pack, outPot, outAcc, N);
}